// Round 23
// baseline (140.798 us; speedup 1.0000x reference)
//
#include <hip/hip_runtime.h>
#include <hip/hip_bf16.h>

#define B_ 4
#define T_ 2048
#define E_ 1024
#define H_ 16
#define HD_ 64

typedef __attribute__((ext_vector_type(8))) short bf16x8;
typedef __attribute__((ext_vector_type(4))) float f32x4;
typedef __attribute__((ext_vector_type(16))) float f32x16;

__device__ inline ushort f2b(float f) {
  union { __hip_bfloat16 h; ushort u; } c;
  c.h = __float2bfloat16(f);
  return c.u;
}
__device__ inline short f2bs(float f) {
  union { __hip_bfloat16 h; short s; } c;
  c.h = __float2bfloat16(f);
  return c.s;
}
__device__ inline int cvtpk(float lo, float hi) {
  int r;
  asm("v_cvt_pk_bf16_f32 %0, %1, %2" : "=v"(r) : "v"(lo), "v"(hi));
  return r;
}
__device__ inline f32x16 zero16() {
  f32x16 z;
#pragma unroll
  for (int i = 0; i < 16; ++i) z[i] = 0.0f;
  return z;
}

// async global->LDS, 16B per lane; lds base must be wave-uniform
__device__ inline void gload16(const ushort* gsrc, ushort* lds_uniform_base) {
  __builtin_amdgcn_global_load_lds(
      (const __attribute__((address_space(1))) void*)gsrc,
      (__attribute__((address_space(3))) void*)lds_uniform_base, 16, 0, 0);
}

// ---------------- merged weight conversion (r18) -----------------------------
__global__ __launch_bounds__(256) void cvt_kernel(const float* __restrict__ Wq,
                                                  ushort* __restrict__ Wt,
                                                  const float* __restrict__ Wp,
                                                  ushort* __restrict__ Wb) {
  int bid = blockIdx.x;
  if (bid < 768) {
    int gtid = bid * 256 + threadIdx.x;   // 0 .. 196607
    int h = gtid / (HD_ * 192);
    int rem = gtid % (HD_ * 192);
    int d = rem / 192;
    int e = rem % 192;
    int v = (e >> 6) * 64 + (e & 3) * 16 + ((e >> 2) & 15);
    Wt[h * (192 * HD_) + v * HD_ + d] = f2b(Wq[gtid]);
  } else {
    int i = ((bid - 768) * 256 + threadIdx.x) * 4;
    float4 f = *reinterpret_cast<const float4*>(Wp + i);
    ushort4 u;
    u.x = f2b(f.x); u.y = f2b(f.y); u.z = f2b(f.z); u.w = f2b(f.w);
    *reinterpret_cast<ushort4*>(Wb + i) = u;
  }
}

// ---------------- QKV projection (r18) ---------------------------------------
__global__ __launch_bounds__(256) void qkv_kernel(const float* __restrict__ x,
                                                  const ushort* __restrict__ Wt,
                                                  const float* __restrict__ bq,
                                                  ushort* __restrict__ Q,
                                                  ushort* __restrict__ K,
                                                  ushort* __restrict__ Vt) {
  const float SCALE = (1.0f / (8.0f + 1e-5f)) * 1.4426950408889634f;
  int wave = threadIdx.x >> 6, lane = threadIdx.x & 63;
  int lo = lane & 15, hi = lane >> 4;
  int bh = blockIdx.y, b = bh >> 4, h = bh & 15;
  int t0 = blockIdx.x * 64 + wave * 16;

  const float* xr = x + (size_t)(b * T_ + t0 + lo) * E_ + h * HD_;
  bf16x8 af[2];
#pragma unroll
  for (int c = 0; c < 2; ++c) {
    float4 f0 = *reinterpret_cast<const float4*>(xr + c * 32 + hi * 8);
    float4 f1 = *reinterpret_cast<const float4*>(xr + c * 32 + hi * 8 + 4);
    bf16x8 v;
    v[0] = f2bs(f0.x); v[1] = f2bs(f0.y); v[2] = f2bs(f0.z); v[3] = f2bs(f0.w);
    v[4] = f2bs(f1.x); v[5] = f2bs(f1.y); v[6] = f2bs(f1.z); v[7] = f2bs(f1.w);
    af[c] = v;
  }

  const ushort* Wh = Wt + h * (192 * HD_);
#pragma unroll
  for (int g = 0; g < 3; ++g) {          // 0=Q, 1=K, 2=V
    f32x4 accg[4];
#pragma unroll
    for (int j = 0; j < 4; ++j) {
      int n0 = (g * 4 + j) * 16;
      bf16x8 bf0 = *reinterpret_cast<const bf16x8*>(Wh + (size_t)(n0 + lo) * HD_ + hi * 8);
      bf16x8 bf1 = *reinterpret_cast<const bf16x8*>(Wh + (size_t)(n0 + lo) * HD_ + 32 + hi * 8);
      f32x4 acc = {0.0f, 0.0f, 0.0f, 0.0f};
      acc = __builtin_amdgcn_mfma_f32_16x16x32_bf16(af[0], bf0, acc, 0, 0, 0);
      acc = __builtin_amdgcn_mfma_f32_16x16x32_bf16(af[1], bf1, acc, 0, 0, 0);
      accg[j] = acc;
    }
    float4 bq4 = *reinterpret_cast<const float4*>(bq + h * 192 + g * 64 + 4 * lo);
    if (g < 2) {
      ushort* dst = (g == 0) ? Q : K;
      float sc = (g == 0) ? SCALE : 1.0f;
#pragma unroll
      for (int r = 0; r < 4; ++r) {
        int t = t0 + hi * 4 + r;
        ushort4 u;
        u.x = f2b((accg[0][r] + bq4.x) * sc);
        u.y = f2b((accg[1][r] + bq4.y) * sc);
        u.z = f2b((accg[2][r] + bq4.z) * sc);
        u.w = f2b((accg[3][r] + bq4.w) * sc);
        *reinterpret_cast<ushort4*>(dst + ((size_t)bh * T_ + t) * HD_ + 4 * lo) = u;
      }
    } else {
      float bj[4] = {bq4.x, bq4.y, bq4.z, bq4.w};
#pragma unroll
      for (int j = 0; j < 4; ++j) {
        int hd = 4 * lo + j;
        ushort4 u;
        u.x = f2b(accg[j][0] + bj[j]);
        u.y = f2b(accg[j][1] + bj[j]);
        u.z = f2b(accg[j][2] + bj[j]);
        u.w = f2b(accg[j][3] + bj[j]);
        int col = t0 + hi * 4 + hd * 8;
        col &= (T_ - 1);
        *reinterpret_cast<ushort4*>(Vt + ((size_t)bh * HD_ + hd) * T_ + col) = u;
      }
    }
  }
}

// ---------------- Flash attention (causal), swapped-operand 32x32 (r15) -----
__global__ __launch_bounds__(512) void attn_kernel(const ushort* __restrict__ Q,
                                                   const ushort* __restrict__ K,
                                                   const ushort* __restrict__ Vt,
                                                   ushort* __restrict__ AO) {
  __shared__ ushort Ks[4][64 * 64];   // [buf][key][dchunk, chunk^=(key&7)]
  __shared__ ushort Vs[4][64 * 64];   // [buf][hd][keychunk, chunk^=(hd&7)]

  int wave = threadIdx.x >> 6, lane = threadIdx.x & 63;
  int q5 = lane & 31, hi5 = lane >> 5;
  int bh = blockIdx.x, b = bh >> 4, h = bh & 15;
  int y = blockIdx.y;
  int qt = (y < 4) ? (7 - y) : (y - 4);   // heavy-first, CU-paired
  int qw = qt * 256 + wave * 32;

  const ushort* Kbh = K + (size_t)bh * T_ * HD_;
  const ushort* Vbh = Vt + (size_t)bh * HD_ * T_;

  bf16x8 qf[4];
#pragma unroll
  for (int ks = 0; ks < 4; ++ks)
    qf[ks] = *reinterpret_cast<const bf16x8*>(
        Q + ((size_t)bh * T_ + qw + q5) * HD_ + ks * 16 + hi5 * 8);

  f32x16 ot[2];
  ot[0] = zero16(); ot[1] = zero16();
  float mreg = -1e30f, lreg = 0.0f;

  int srow = lane >> 3;   // 0..7
  int sch = lane & 7;     // 16B chunk within 128B row

  int ntiles = qt * 4 + 4;   // always >= 4 and even

#define STAGE(BUF, TILE)                                                        \
  {                                                                             \
    int kt_ = (TILE) << 6;                                                      \
    int row = wave * 8 + srow;                                                  \
    const ushort* gk = Kbh + (size_t)(kt_ + row) * HD_ + ((sch ^ (row & 7)) * 8); \
    gload16(gk, &Ks[BUF][(wave * 8) * 64]);                                     \
    int col = (kt_ + ((sch ^ (row & 7)) + row) * 8) & (T_ - 1);                 \
    const ushort* gv = Vbh + (size_t)row * T_ + col;                            \
    gload16(gv, &Vs[BUF][(wave * 8) * 64]);                                     \
  }

  auto compute_tile = [&](int tile, int buf) {
    int kt = tile << 6;
    if (kt > qw + 31) return;   // wave-uniform causal predicate
    f32x16 s[2];
#pragma unroll
    for (int g = 0; g < 2; ++g) {
      int krow = g * 32 + q5;
      bf16x8 kf[4];
#pragma unroll
      for (int ks = 0; ks < 4; ++ks)
        kf[ks] = *reinterpret_cast<const bf16x8*>(
            &Ks[buf][krow * 64 + (((2 * ks + hi5) ^ (krow & 7)) * 8)]);
      f32x16 acc = zero16();
      __builtin_amdgcn_s_setprio(1);
#pragma unroll
      for (int ks = 0; ks < 4; ++ks)
        acc = __builtin_amdgcn_mfma_f32_32x32x16_bf16(kf[ks], qf[ks], acc, 0, 0, 0);
      __builtin_amdgcn_s_setprio(0);
      s[g] = acc;
    }
    if (kt + 63 > qw) {
      int q = qw + q5;
#pragma unroll
      for (int g = 0; g < 2; ++g)
#pragma unroll
        for (int r = 0; r < 16; ++r) {
          int key = kt + g * 32 + (r & 3) + 8 * (r >> 2) + 4 * hi5;
          if (key > q) s[g][r] = -1e30f;
        }
    }
    float t8[8];
#pragma unroll
    for (int i = 0; i < 8; ++i)
      t8[i] = fmaxf(fmaxf(s[0][i], s[0][i + 8]), fmaxf(s[1][i], s[1][i + 8]));
    float mx = fmaxf(fmaxf(fmaxf(t8[0], t8[1]), fmaxf(t8[2], t8[3])),
                     fmaxf(fmaxf(t8[4], t8[5]), fmaxf(t8[6], t8[7])));
    mx = fmaxf(mx, __shfl_xor(mx, 32));
    float nm = fmaxf(mreg, mx);
    float alpha = exp2f(mreg - nm);
    mreg = nm;
#pragma unroll
    for (int g = 0; g < 2; ++g)
#pragma unroll
      for (int r = 0; r < 16; ++r)
        s[g][r] = exp2f(s[g][r] - nm);
    float u8[8];
#pragma unroll
    for (int i = 0; i < 8; ++i)
      u8[i] = (s[0][i] + s[0][i + 8]) + (s[1][i] + s[1][i + 8]);
    float rs = ((u8[0] + u8[1]) + (u8[2] + u8[3])) + ((u8[4] + u8[5]) + (u8[6] + u8[7]));
    rs += __shfl_xor(rs, 32);
    lreg = lreg * alpha + rs;
#pragma unroll
    for (int nh = 0; nh < 2; ++nh)
#pragma unroll
      for (int r = 0; r < 16; ++r) ot[nh][r] *= alpha;

    bf16x8 pb4[4];
#pragma unroll
    for (int ks = 0; ks < 4; ++ks) {
      int g = ks >> 1;
      int R0 = 2 * (ks & 1), R1 = R0 + 1;
      int a0w0 = cvtpk(s[g][4 * R0 + 0], s[g][4 * R0 + 1]);
      int a0w1 = cvtpk(s[g][4 * R0 + 2], s[g][4 * R0 + 3]);
      int a1w0 = cvtpk(s[g][4 * R1 + 0], s[g][4 * R1 + 1]);
      int a1w1 = cvtpk(s[g][4 * R1 + 2], s[g][4 * R1 + 3]);
      int pA0w0 = __shfl_xor(a0w0, 32);
      int pA0w1 = __shfl_xor(a0w1, 32);
      int pA1w0 = __shfl_xor(a1w0, 32);
      int pA1w1 = __shfl_xor(a1w1, 32);
      int4 w;
      w.x = hi5 ? pA1w0 : a0w0;   // keys base+0,1
      w.y = hi5 ? pA1w1 : a0w1;   // keys base+2,3
      w.z = hi5 ? a1w0 : pA0w0;   // keys base+4,5
      w.w = hi5 ? a1w1 : pA0w1;   // keys base+6,7
      pb4[ks] = *reinterpret_cast<bf16x8*>(&w);
    }
#pragma unroll
    for (int nh = 0; nh < 2; ++nh) {
      int vrow = nh * 32 + q5;
      bf16x8 vf[4];
#pragma unroll
      for (int ks = 0; ks < 4; ++ks)
        vf[ks] = *reinterpret_cast<const bf16x8*>(
            &Vs[buf][vrow * 64 + (((2 * ks + hi5) ^ (vrow & 7)) * 8)]);
      __builtin_amdgcn_s_setprio(1);
#pragma unroll
      for (int ks = 0; ks < 4; ++ks)
        ot[nh] = __builtin_amdgcn_mfma_f32_32x32x16_bf16(vf[ks], pb4[ks], ot[nh], 0, 0, 0);
      __builtin_amdgcn_s_setprio(0);
    }
  };

  STAGE(0, 0);
  STAGE(1, 1);

  int npairs = ntiles >> 1;
  for (int p = 0; p < npairs; ++p) {
    int t0 = 2 * p, t1 = 2 * p + 1;
    asm volatile("s_waitcnt vmcnt(0)" ::: "memory");
    __builtin_amdgcn_s_barrier();   // raw barrier (no drain re-insertion)
    {
      int pr0 = t0 + 2, pr1 = t0 + 3;
      int s0 = (pr0 < ntiles) ? pr0 : 0;
      int s1 = (pr1 < ntiles) ? pr1 : 0;
      STAGE(pr0 & 3, s0);
      STAGE(pr1 & 3, s1);
    }
    compute_tile(t0, t0 & 3);
    compute_tile(t1, t1 & 3);
  }
#undef STAGE

  float inv = 1.0f / lreg;
  int t = qw + q5;
  ushort* aop = AO + ((size_t)(b * T_ + t) * H_ + h) * HD_;
#pragma unroll
  for (int nh = 0; nh < 2; ++nh)
#pragma unroll
    for (int R = 0; R < 4; ++R) {
      ushort4 u;
      u.x = f2b(ot[nh][4 * R + 0] * inv);
      u.y = f2b(ot[nh][4 * R + 1] * inv);
      u.z = f2b(ot[nh][4 * R + 2] * inv);
      u.w = f2b(ot[nh][4 * R + 3] * inv);
      *reinterpret_cast<ushort4*>(aop + nh * 32 + 8 * R + 4 * hi5) = u;
    }
}

// ---------------- Output projection, BK=64, 8 waves (512 thr) ----------------
// [8192,1024] x [1024,1024]^T + bias. 128x128 tile, BK=64, 8 waves:
// wr=wave>>1 (32-row slab), wc=wave&1 (64-col slab); per-wave 32x64 out.
// 16 waves/CU (4/SIMD) to hide the per-step drain. LDS [128][64] x2 dbuf,
// lane map 8 rows/instr (lane>>3), chunk lane&7, swizzle chunk^=(row&7).
__global__ __launch_bounds__(512) void proj_kernel(const ushort* __restrict__ A,
                                                   const ushort* __restrict__ Wb,
                                                   const float* __restrict__ bias,
                                                   float* __restrict__ out) {
  __shared__ ushort As[2][128 * 64];
  __shared__ ushort Bs[2][128 * 64];
  int tid = threadIdx.x;
  int wave = tid >> 6, lane = tid & 63;
  int lo = lane & 15, hi = lane >> 4;
  int wr = wave >> 1, wc = wave & 1;
  int m0 = blockIdx.y * 128, n0 = blockIdx.x * 128;

  int srow8 = lane >> 3;     // 0..7 (row within 8-row group)
  int sch8 = lane & 7;       // 16B chunk within 128B row
  int swz = sch8 ^ srow8;    // pre-swizzled source chunk (row&7 == srow8)

#define PSTAGE(BUF, K0)                                                          \
  {                                                                              \
    _Pragma("unroll")                                                            \
    for (int rep = 0; rep < 2; ++rep) {                                          \
      int row = wave * 16 + rep * 8 + srow8;                                     \
      gload16(A + (size_t)(m0 + row) * E_ + (K0) + swz * 8,                      \
              &As[BUF][(wave * 16 + rep * 8) * 64]);                             \
      gload16(Wb + (size_t)(n0 + row) * E_ + (K0) + swz * 8,                     \
              &Bs[BUF][(wave * 16 + rep * 8) * 64]);                             \
    }                                                                            \
  }

  f32x4 acc[2][4] = {};
  PSTAGE(0, 0);
  asm volatile("s_waitcnt vmcnt(0)" ::: "memory");
  __syncthreads();

  int cur = 0;
  for (int k0 = 0; k0 < E_; k0 += 64) {
    int kpre = (k0 + 64) & (E_ - 1);   // last iter harmlessly re-fetches k=0
    PSTAGE(cur ^ 1, kpre);
#pragma unroll
    for (int hh = 0; hh < 2; ++hh) {   // two K=32 sub-tiles of the 64-col buf
      bf16x8 af[2], bfr[4];
#pragma unroll
      for (int i = 0; i < 2; ++i) {
        int row = wr * 32 + i * 16 + lo;
        af[i] = *reinterpret_cast<const bf16x8*>(
            &As[cur][row * 64 + (((hh * 4 + hi) ^ (row & 7)) * 8)]);
      }
#pragma unroll
      for (int j = 0; j < 4; ++j) {
        int row = wc * 64 + j * 16 + lo;
        bfr[j] = *reinterpret_cast<const bf16x8*>(
            &Bs[cur][row * 64 + (((hh * 4 + hi) ^ (row & 7)) * 8)]);
      }
      __builtin_amdgcn_s_setprio(1);
#pragma unroll
      for (int i = 0; i < 2; ++i)
#pragma unroll
        for (int j = 0; j < 4; ++j)
          acc[i][j] = __builtin_amdgcn_mfma_f32_16x16x32_bf16(af[i], bfr[j], acc[i][j], 0, 0, 0);
      __builtin_amdgcn_s_setprio(0);
    }
    asm volatile("s_waitcnt vmcnt(0)" ::: "memory");
    __syncthreads();
    cur ^= 1;
  }
#undef PSTAGE

#pragma unroll
  for (int i = 0; i < 2; ++i)
#pragma unroll
    for (int r = 0; r < 4; ++r) {
      int mm = m0 + wr * 32 + i * 16 + hi * 4 + r;
      float* orow = out + (size_t)mm * E_ + n0 + wc * 64;
#pragma unroll
      for (int j = 0; j < 4; ++j)
        orow[j * 16 + lo] = acc[i][j][r] + bias[n0 + wc * 64 + j * 16 + lo];
    }
}

extern "C" void kernel_launch(void* const* d_in, const int* in_sizes, int n_in,
                              void* d_out, int out_size, void* d_ws, size_t ws_size,
                              hipStream_t stream) {
  (void)in_sizes; (void)n_in; (void)out_size; (void)ws_size;
  const float* x  = (const float*)d_in[0];
  const float* Wq = (const float*)d_in[1];
  const float* bq = (const float*)d_in[2];
  const float* Wp = (const float*)d_in[3];
  const float* bp = (const float*)d_in[4];
  float* out = (float*)d_out;

  const size_t NQ = (size_t)B_ * H_ * T_ * HD_;
  ushort* ws = (ushort*)d_ws;
  ushort* Q  = ws;
  ushort* K  = ws + NQ;
  ushort* Vt = ws + 2 * NQ;
  ushort* AO = ws + 3 * NQ;
  ushort* Wb = ws + 4 * NQ;
  ushort* Wt = ws + 4 * NQ + (size_t)E_ * E_;

  cvt_kernel<<<dim3(1792), dim3(256), 0, stream>>>(Wq, Wt, Wp, Wb);
  qkv_kernel<<<dim3(T_ / 64, B_ * H_), dim3(256), 0, stream>>>(x, Wt, bq, Q, K, Vt);
  attn_kernel<<<dim3(B_ * H_, 8), dim3(512), 0, stream>>>(Q, K, Vt, AO);
  proj_kernel<<<dim3(E_ / 128, (B_ * T_) / 128), dim3(512), 0, stream>>>(AO, Wb, bp, out);
}